// Round 8
// baseline (10.504 us; speedup 1.0000x reference)
//
#include <hip/hip_runtime.h>
#include <math.h>

#define FXc 300.0f
#define FYc 300.0f
#define CXc 128.0f
#define CYc 128.0f
#define BGc 1.0f
#define EPS2Dc 0.3f
#define NEARc 0.01f
#define C0c 0.28209479177387814f

#define MAXP 512   // max points (N_PTS == 512)
#define SEG  8     // depth segments composited in parallel (2 px per thread)

// Fully fused, depth-parallel: each block owns a 16x16 tile, 1024 threads.
// Threads 0..511 preprocess one point each; cull = EXACT min-sigma-over-tile
// test. Survivors ballot-compact, stable rank-sort by z, scatter into a
// depth-sorted LDS table (8 floats/splat: colors cr,cg packed bf16).
// Composite: 8 depth segments x 128 threads x 2 pixels (same column, rows
// r and r+8), folded associatively.
__global__ void __launch_bounds__(1024)
gs_fused(const float* __restrict__ cam,
         const float* __restrict__ means,
         const float* __restrict__ quats,
         const float* __restrict__ scales,
         const float* __restrict__ opacs,
         const float* __restrict__ sh0,
         const int* __restrict__ img_w_p,
         float* __restrict__ out,
         int n, int npix)
{
    __shared__ float4 spts[MAXP][2];              // depth-sorted survivor params
    __shared__ __align__(16) float zc[MAXP + 4];  // compacted survivor z (+INF pad)
    __shared__ int scnt[MAXP / 64];
    __shared__ int sbase[MAXP / 64 + 1];
    __shared__ float4 comb[SEG - 1][256];         // per-segment partials (r,g,b,T)

    const int lt   = threadIdx.x;
    const int wave = lt >> 6;

    const int W = *img_w_p;
    const int tiles_x = W >> 4;                   // assumes W % 16 == 0
    const int tx = (blockIdx.x % tiles_x) << 4;
    const int ty = (blockIdx.x / tiles_x) << 4;
    const float tx0 = (float)tx + 0.5f, tx1 = (float)tx + 15.5f;
    const float ty0 = (float)ty + 0.5f, ty1 = (float)ty + 15.5f;

    const int nchunks = (n + 63) >> 6;            // <= 8

    // ---------------- preprocess: one point per thread (lt < 512) -------------
    float pmx = 0.f, pmy = 0.f, pA_ = 0.f, pB_ = 0.f, pC_ = 0.f;
    float pop = 0.f, pcr = 0.f, pcg = 0.f, pcb = 0.f, pz = 0.f;
    unsigned long long mreg = 0ull;
    bool phit = false;

    if (lt < MAXP) {
        // camera: c2w = [M|b]; viewmat = inv(c2w) with rows 1,2 negated
        const float a00 = cam[0], a01 = cam[1], a02 = cam[2],  b0 = cam[3];
        const float a10 = cam[4], a11 = cam[5], a12 = cam[6],  b1 = cam[7];
        const float a20 = cam[8], a21 = cam[9], a22 = cam[10], b2 = cam[11];
        const float det3 = a00*(a11*a22 - a12*a21) - a01*(a10*a22 - a12*a20) + a02*(a10*a21 - a11*a20);
        const float id = 1.0f / det3;
        const float i00 = (a11*a22 - a12*a21)*id, i01 = (a02*a21 - a01*a22)*id, i02 = (a01*a12 - a02*a11)*id;
        const float i10 = (a12*a20 - a10*a22)*id, i11 = (a00*a22 - a02*a20)*id, i12 = (a02*a10 - a00*a12)*id;
        const float i20 = (a10*a21 - a11*a20)*id, i21 = (a01*a20 - a00*a21)*id, i22 = (a00*a11 - a01*a10)*id;
        const float R00 = i00,  R01 = i01,  R02 = i02;
        const float R10 = -i10, R11 = -i11, R12 = -i12;
        const float R20 = -i20, R21 = -i21, R22 = -i22;
        const float t0 = -(i00*b0 + i01*b1 + i02*b2);
        const float t1 = (i10*b0 + i11*b1 + i12*b2);
        const float t2 = (i20*b0 + i21*b1 + i22*b2);
        const float limx_e = 1.3f * (0.5f * (float)W / FXc);
        const float limy_e = limx_e;

        const int p = lt;
        bool hit = false;
        if (p < n) {
            const float m0 = means[3*p], m1 = means[3*p+1], m2 = means[3*p+2];
            const float px_ = R00*m0 + R01*m1 + R02*m2 + t0;
            const float py_ = R10*m0 + R11*m1 + R12*m2 + t1;
            const float pz_ = R20*m0 + R21*m1 + R22*m2 + t2;

            bool valid = pz_ > NEARc;
            const float zs = valid ? pz_ : 1.0f;
            const float rz = 1.0f / zs;

            float qw = quats[4*p], qx = quats[4*p+1], qy = quats[4*p+2], qz = quats[4*p+3];
            const float qn = rsqrtf(qw*qw + qx*qx + qy*qy + qz*qz);
            qw *= qn; qx *= qn; qy *= qn; qz *= qn;
            const float Rq00 = 1.f - 2.f*(qy*qy + qz*qz), Rq01 = 2.f*(qx*qy - qw*qz), Rq02 = 2.f*(qx*qz + qw*qy);
            const float Rq10 = 2.f*(qx*qy + qw*qz), Rq11 = 1.f - 2.f*(qx*qx + qz*qz), Rq12 = 2.f*(qy*qz - qw*qx);
            const float Rq20 = 2.f*(qx*qz - qw*qy), Rq21 = 2.f*(qy*qz + qw*qx), Rq22 = 1.f - 2.f*(qx*qx + qy*qy);

            const float e0 = __expf(scales[3*p]), e1 = __expf(scales[3*p+1]), e2 = __expf(scales[3*p+2]);
            const float M00 = Rq00*e0, M01 = Rq01*e1, M02 = Rq02*e2;
            const float M10 = Rq10*e0, M11 = Rq11*e1, M12 = Rq12*e2;
            const float M20 = Rq20*e0, M21 = Rq21*e1, M22 = Rq22*e2;

            const float S00 = M00*M00 + M01*M01 + M02*M02;
            const float S01 = M00*M10 + M01*M11 + M02*M12;
            const float S02 = M00*M20 + M01*M21 + M02*M22;
            const float S11 = M10*M10 + M11*M11 + M12*M12;
            const float S12 = M10*M20 + M11*M21 + M12*M22;
            const float S22 = M20*M20 + M21*M21 + M22*M22;

            const float U00 = R00*S00 + R01*S01 + R02*S02;
            const float U01 = R00*S01 + R01*S11 + R02*S12;
            const float U02 = R00*S02 + R01*S12 + R02*S22;
            const float U10 = R10*S00 + R11*S01 + R12*S02;
            const float U11 = R10*S01 + R11*S11 + R12*S12;
            const float U12 = R10*S02 + R11*S12 + R12*S22;
            const float U20 = R20*S00 + R21*S01 + R22*S02;
            const float U21 = R20*S01 + R21*S11 + R22*S12;
            const float U22 = R20*S02 + R21*S12 + R22*S22;

            const float C00 = U00*R00 + U01*R01 + U02*R02;
            const float C01 = U00*R10 + U01*R11 + U02*R12;
            const float C02 = U00*R20 + U01*R21 + U02*R22;
            const float C11 = U10*R10 + U11*R11 + U12*R12;
            const float C12 = U10*R20 + U11*R21 + U12*R22;
            const float C22 = U20*R20 + U21*R21 + U22*R22;

            const float txc = zs * fminf(fmaxf(px_*rz, -limx_e), limx_e);
            const float tyc = zs * fminf(fmaxf(py_*rz, -limy_e), limy_e);
            const float ja0 = FXc * rz;
            const float ja2 = -FXc * txc * rz * rz;
            const float jb1 = FYc * rz;
            const float jb2 = -FYc * tyc * rz * rz;

            const float c2d00 = ja0*ja0*C00 + 2.f*ja0*ja2*C02 + ja2*ja2*C22 + EPS2Dc;
            const float c2d01 = ja0*jb1*C01 + ja0*jb2*C02 + ja2*jb1*C12 + ja2*jb2*C22;
            const float c2d11 = jb1*jb1*C11 + 2.f*jb1*jb2*C12 + jb2*jb2*C22 + EPS2Dc;

            const float det2 = c2d00*c2d11 - c2d01*c2d01;
            valid = valid && (det2 > 1e-12f);
            const float rdet = 1.0f / (valid ? det2 : 1.0f);
            pA_ = c2d11 * rdet;             // conic a  (>0)
            pB_ = -c2d01 * rdet;            // conic b
            pC_ = c2d00 * rdet;             // conic c  (>0)

            pmx = FXc * px_ * rz + CXc;
            pmy = FYc * py_ * rz + CYc;

            pcr = fmaxf(C0c * sh0[3*p+0] + 0.5f, 0.0f);
            pcg = fmaxf(C0c * sh0[3*p+1] + 0.5f, 0.0f);
            pcb = fmaxf(C0c * sh0[3*p+2] + 0.5f, 0.0f);
            pop = 1.0f / (1.0f + __expf(-opacs[p]));
            pz  = pz_;

            // ---- EXACT cull: min over tile rect of sigma vs log(255*op) ----
            if (valid) {
                const float a_ = pA_, b_ = pB_, c_ = pC_;
                const float dx0 = tx0 - pmx, dx1 = tx1 - pmx;
                const float dy0 = ty0 - pmy, dy1 = ty1 - pmy;
                float smin;
                if (dx0 <= 0.f && 0.f <= dx1 && dy0 <= 0.f && 0.f <= dy1) {
                    smin = 0.f;
                } else {
                    const float ra = 1.0f / a_, rc = 1.0f / c_;
                    float yy = fminf(fmaxf(-b_ * dx0 * rc, dy0), dy1);
                    float s0 = 0.5f*a_*dx0*dx0 + b_*dx0*yy + 0.5f*c_*yy*yy;
                    yy = fminf(fmaxf(-b_ * dx1 * rc, dy0), dy1);
                    float s1 = 0.5f*a_*dx1*dx1 + b_*dx1*yy + 0.5f*c_*yy*yy;
                    float xx = fminf(fmaxf(-b_ * dy0 * ra, dx0), dx1);
                    float s2 = 0.5f*a_*xx*xx + b_*xx*dy0 + 0.5f*c_*dy0*dy0;
                    xx = fminf(fmaxf(-b_ * dy1 * ra, dx0), dx1);
                    float s3 = 0.5f*a_*xx*xx + b_*xx*dy1 + 0.5f*c_*dy1*dy1;
                    smin = fminf(fminf(s0, s1), fminf(s2, s3));
                }
                hit = (smin <= __logf(pop * 255.0f) + 1e-3f);
            }
        }
        phit = hit;
        mreg = __ballot(hit);
        if ((lt & 63) == 0) scnt[wave] = __popcll(mreg);
    }
    __syncthreads();

    if (lt == 0) {
        int acc = 0;
        for (int c = 0; c < nchunks; ++c) { sbase[c] = acc; acc += scnt[c]; }
        sbase[nchunks] = acc;
    }
    __syncthreads();
    const int k = sbase[nchunks];

    // compact survivor z's (original-index order == stable key order)
    int pslot = -1;
    if (lt < MAXP && phit) {
        pslot = sbase[wave] + __popcll(mreg & ((1ull << (lt & 63)) - 1ull));
        zc[pslot] = pz;
    }
    if (lt < 4) zc[k + lt] = INFINITY;
    __syncthreads();

    // stable rank-sort of survivors; scatter params from registers.
    // cr,cg packed as round-to-nearest bf16 pair (color abs err <= ~1e-3).
    if (pslot >= 0) {
        const float za = pz;
        const int sa = pslot;
        int rank = 0;
        const float4* z4 = (const float4*)zc;
        const int k4 = (k + 3) >> 2;
        for (int j4 = 0; j4 < k4; ++j4) {
            const float4 v = z4[j4];
            const int j = j4 << 2;
            rank += (v.x < za || (v.x == za && (j+0) < sa));
            rank += (v.y < za || (v.y == za && (j+1) < sa));
            rank += (v.z < za || (v.z == za && (j+2) < sa));
            rank += (v.w < za || (v.w == za && (j+3) < sa));
        }
        unsigned ur = __float_as_uint(pcr);
        ur = (ur + 0x7FFFu + ((ur >> 16) & 1u)) & 0xFFFF0000u;
        unsigned ug = __float_as_uint(pcg);
        ug = (ug + 0x7FFFu + ((ug >> 16) & 1u)) >> 16;
        const float crcg = __uint_as_float(ur | ug);
        spts[rank][0] = make_float4(pmx, pmy, pA_, pB_);
        spts[rank][1] = make_float4(pC_, pop, crcg, pcb);
    }
    __syncthreads();

    // ------- depth-parallel compositing: SEG segments x 128 thr x 2 px -------
    const int s  = lt >> 7;           // segment 0..7 (front..back)
    const int p0 = lt & 127;          // pixel 0 (rows 0..7), pixel 1 = p0+128
    const int col  = tx + (p0 & 15);
    const int row0 = ty + (p0 >> 4);
    const float px  = (float)col + 0.5f;
    const float py0 = (float)row0 + 0.5f;
    const float py1 = py0 + 8.0f;

    const int beg = (k * s) >> 3;             // SEG == 8
    const int end = (k * (s + 1)) >> 3;

    float T0 = 1.0f, r0 = 0.f, g0 = 0.f, b0 = 0.f;
    float T1 = 1.0f, r1 = 0.f, g1 = 0.f, b1 = 0.f;
    for (int base = beg; base < end; base += 4) {
        const int lim = (base + 4 < end) ? base + 4 : end;
        #pragma unroll 4
        for (int i = base; i < lim; ++i) {
            const float4 a4 = spts[i][0];        // mx, my, cA, cB
            const float4 b4 = spts[i][1];        // cC, op, crcg(bf16x2), cb
            const unsigned uc = __float_as_uint(b4.z);
            const float crf = __uint_as_float(uc & 0xFFFF0000u);
            const float cgf = __uint_as_float(uc << 16);
            const float cbv = b4.w;

            const float dx  = px  - a4.x;
            const float dy0 = py0 - a4.y;
            const float dy1 = py1 - a4.y;

            const float sg0 = 0.5f * (a4.z*dx*dx + b4.x*dy0*dy0) + a4.w*dx*dy0;
            float al0 = b4.y * __expf(-sg0);
            al0 = fminf(al0, 0.999f);
            al0 = ((sg0 >= 0.0f) && (al0 >= (1.0f/255.0f))) ? al0 : 0.0f;
            const float w0 = T0 * al0;
            r0 += w0 * crf; g0 += w0 * cgf; b0 += w0 * cbv;
            T0 = __builtin_fmaf(-al0, T0, T0);

            const float sg1 = 0.5f * (a4.z*dx*dx + b4.x*dy1*dy1) + a4.w*dx*dy1;
            float al1 = b4.y * __expf(-sg1);
            al1 = fminf(al1, 0.999f);
            al1 = ((sg1 >= 0.0f) && (al1 >= (1.0f/255.0f))) ? al1 : 0.0f;
            const float w1 = T1 * al1;
            r1 += w1 * crf; g1 += w1 * cgf; b1 += w1 * cbv;
            T1 = __builtin_fmaf(-al1, T1, T1);
        }
        if (!__any(fmaxf(T0, T1) > 1e-4f)) break;   // tail err <= ~1e-4
    }

    if (s > 0) {
        comb[s - 1][p0]       = make_float4(r0, g0, b0, T0);
        comb[s - 1][p0 + 128] = make_float4(r1, g1, b1, T1);
    }
    __syncthreads();

    if (s == 0) {
        // fold front-to-back for both pixels
        float rr = r0, gg = g0, bb = b0, Tt = T0;
        #pragma unroll
        for (int ss = 0; ss < SEG - 1; ++ss) {
            const float4 f = comb[ss][p0];
            rr += Tt * f.x; gg += Tt * f.y; bb += Tt * f.z; Tt *= f.w;
        }
        rr += Tt * BGc; gg += Tt * BGc; bb += Tt * BGc;
        int opix = row0 * W + col;
        out[3*opix + 0] = rr;
        out[3*opix + 1] = gg;
        out[3*opix + 2] = bb;
        out[3*npix + opix] = 1.0f - Tt;

        rr = r1; gg = g1; bb = b1; Tt = T1;
        #pragma unroll
        for (int ss = 0; ss < SEG - 1; ++ss) {
            const float4 f = comb[ss][p0 + 128];
            rr += Tt * f.x; gg += Tt * f.y; bb += Tt * f.z; Tt *= f.w;
        }
        rr += Tt * BGc; gg += Tt * BGc; bb += Tt * BGc;
        opix = (row0 + 8) * W + col;
        out[3*opix + 0] = rr;
        out[3*opix + 1] = gg;
        out[3*opix + 2] = bb;
        out[3*npix + opix] = 1.0f - Tt;
    }
}

extern "C" void kernel_launch(void* const* d_in, const int* in_sizes, int n_in,
                              void* d_out, int out_size, void* d_ws, size_t ws_size,
                              hipStream_t stream) {
    const float* cam    = (const float*)d_in[0];
    const float* means  = (const float*)d_in[1];
    const float* quats  = (const float*)d_in[2];
    const float* scales = (const float*)d_in[3];
    const float* opacs  = (const float*)d_in[4];
    const float* sh0    = (const float*)d_in[5];
    // d_in[6] = shN (unused by the reference render)
    const int* img_w = (const int*)d_in[8];

    const int n = in_sizes[4];            // N_PTS (== 512 for this problem)
    const int npix = out_size / 4;        // 3 color + 1 alpha per pixel

    const int blocks = npix / 256;        // one 16x16 tile per block
    gs_fused<<<blocks, 1024, 0, stream>>>(cam, means, quats, scales, opacs, sh0,
                                          img_w, (float*)d_out, n, npix);
}

// Round 9
// 10.290 us; speedup vs baseline: 1.0208x; 1.0208x over previous
//
#include <hip/hip_runtime.h>
#include <math.h>

#define FXc 300.0f
#define FYc 300.0f
#define CXc 128.0f
#define CYc 128.0f
#define BGc 1.0f
#define EPS2Dc 0.3f
#define NEARc 0.01f
#define C0c 0.28209479177387814f

#define MAXP 512   // max points (N_PTS == 512)
#define SEG  8     // depth segments composited in parallel (2 px per thread)

typedef float v2f __attribute__((ext_vector_type(2)));

// Fully fused, depth-parallel: each block owns a 16x16 tile, 1024 threads.
// Threads 0..511 preprocess one point each; cull = EXACT min-sigma-over-tile
// test. Survivors ballot-compact, stable rank-sort by z, scatter into a
// depth-sorted LDS table (8 floats/splat: 0.5a,b,0.5c pre-scaled, cr/cg bf16).
// Composite: 8 depth segments x 128 threads x 2 pixels, with packed-f32
// (v_pk_*) math on the pixel pair, folded associatively.
__global__ void __launch_bounds__(1024)
gs_fused(const float* __restrict__ cam,
         const float* __restrict__ means,
         const float* __restrict__ quats,
         const float* __restrict__ scales,
         const float* __restrict__ opacs,
         const float* __restrict__ sh0,
         const int* __restrict__ img_w_p,
         float* __restrict__ out,
         int n, int npix)
{
    __shared__ float4 spts[MAXP][2];              // depth-sorted survivor params
    __shared__ __align__(16) float zc[MAXP + 4];  // compacted survivor z (+INF pad)
    __shared__ int scnt[MAXP / 64];
    __shared__ int sbase[MAXP / 64 + 1];
    __shared__ float4 comb[SEG - 1][256];         // per-segment partials (r,g,b,T)

    const int lt   = threadIdx.x;
    const int wave = lt >> 6;

    const int W = *img_w_p;
    const int tiles_x = W >> 4;                   // assumes W % 16 == 0
    const int tx = (blockIdx.x % tiles_x) << 4;
    const int ty = (blockIdx.x / tiles_x) << 4;
    const float tx0 = (float)tx + 0.5f, tx1 = (float)tx + 15.5f;
    const float ty0 = (float)ty + 0.5f, ty1 = (float)ty + 15.5f;

    const int nchunks = (n + 63) >> 6;            // <= 8

    // ---------------- preprocess: one point per thread (lt < 512) -------------
    float pmx = 0.f, pmy = 0.f, pA_ = 0.f, pB_ = 0.f, pC_ = 0.f;
    float pop = 0.f, pcr = 0.f, pcg = 0.f, pcb = 0.f, pz = 0.f;
    unsigned long long mreg = 0ull;
    bool phit = false;

    if (lt < MAXP) {
        // camera: c2w = [M|b]; viewmat = inv(c2w) with rows 1,2 negated
        const float a00 = cam[0], a01 = cam[1], a02 = cam[2],  b0 = cam[3];
        const float a10 = cam[4], a11 = cam[5], a12 = cam[6],  b1 = cam[7];
        const float a20 = cam[8], a21 = cam[9], a22 = cam[10], b2 = cam[11];
        const float det3 = a00*(a11*a22 - a12*a21) - a01*(a10*a22 - a12*a20) + a02*(a10*a21 - a11*a20);
        const float id = 1.0f / det3;
        const float i00 = (a11*a22 - a12*a21)*id, i01 = (a02*a21 - a01*a22)*id, i02 = (a01*a12 - a02*a11)*id;
        const float i10 = (a12*a20 - a10*a22)*id, i11 = (a00*a22 - a02*a20)*id, i12 = (a02*a10 - a00*a12)*id;
        const float i20 = (a10*a21 - a11*a20)*id, i21 = (a01*a20 - a00*a21)*id, i22 = (a00*a11 - a01*a10)*id;
        const float R00 = i00,  R01 = i01,  R02 = i02;
        const float R10 = -i10, R11 = -i11, R12 = -i12;
        const float R20 = -i20, R21 = -i21, R22 = -i22;
        const float t0 = -(i00*b0 + i01*b1 + i02*b2);
        const float t1 = (i10*b0 + i11*b1 + i12*b2);
        const float t2 = (i20*b0 + i21*b1 + i22*b2);
        const float limx_e = 1.3f * (0.5f * (float)W / FXc);
        const float limy_e = limx_e;

        const int p = lt;
        bool hit = false;
        if (p < n) {
            const float m0 = means[3*p], m1 = means[3*p+1], m2 = means[3*p+2];
            const float px_ = R00*m0 + R01*m1 + R02*m2 + t0;
            const float py_ = R10*m0 + R11*m1 + R12*m2 + t1;
            const float pz_ = R20*m0 + R21*m1 + R22*m2 + t2;

            bool valid = pz_ > NEARc;
            const float zs = valid ? pz_ : 1.0f;
            const float rz = 1.0f / zs;

            float qw = quats[4*p], qx = quats[4*p+1], qy = quats[4*p+2], qz = quats[4*p+3];
            const float qn = rsqrtf(qw*qw + qx*qx + qy*qy + qz*qz);
            qw *= qn; qx *= qn; qy *= qn; qz *= qn;
            const float Rq00 = 1.f - 2.f*(qy*qy + qz*qz), Rq01 = 2.f*(qx*qy - qw*qz), Rq02 = 2.f*(qx*qz + qw*qy);
            const float Rq10 = 2.f*(qx*qy + qw*qz), Rq11 = 1.f - 2.f*(qx*qx + qz*qz), Rq12 = 2.f*(qy*qz - qw*qx);
            const float Rq20 = 2.f*(qx*qz - qw*qy), Rq21 = 2.f*(qy*qz + qw*qx), Rq22 = 1.f - 2.f*(qx*qx + qy*qy);

            const float e0 = __expf(scales[3*p]), e1 = __expf(scales[3*p+1]), e2 = __expf(scales[3*p+2]);
            const float M00 = Rq00*e0, M01 = Rq01*e1, M02 = Rq02*e2;
            const float M10 = Rq10*e0, M11 = Rq11*e1, M12 = Rq12*e2;
            const float M20 = Rq20*e0, M21 = Rq21*e1, M22 = Rq22*e2;

            const float S00 = M00*M00 + M01*M01 + M02*M02;
            const float S01 = M00*M10 + M01*M11 + M02*M12;
            const float S02 = M00*M20 + M01*M21 + M02*M22;
            const float S11 = M10*M10 + M11*M11 + M12*M12;
            const float S12 = M10*M20 + M11*M21 + M12*M22;
            const float S22 = M20*M20 + M21*M21 + M22*M22;

            const float U00 = R00*S00 + R01*S01 + R02*S02;
            const float U01 = R00*S01 + R01*S11 + R02*S12;
            const float U02 = R00*S02 + R01*S12 + R02*S22;
            const float U10 = R10*S00 + R11*S01 + R12*S02;
            const float U11 = R10*S01 + R11*S11 + R12*S12;
            const float U12 = R10*S02 + R11*S12 + R12*S22;
            const float U20 = R20*S00 + R21*S01 + R22*S02;
            const float U21 = R20*S01 + R21*S11 + R22*S12;
            const float U22 = R20*S02 + R21*S12 + R22*S22;

            const float C00 = U00*R00 + U01*R01 + U02*R02;
            const float C01 = U00*R10 + U01*R11 + U02*R12;
            const float C02 = U00*R20 + U01*R21 + U02*R22;
            const float C11 = U10*R10 + U11*R11 + U12*R12;
            const float C12 = U10*R20 + U11*R21 + U12*R22;
            const float C22 = U20*R20 + U21*R21 + U22*R22;

            const float txc = zs * fminf(fmaxf(px_*rz, -limx_e), limx_e);
            const float tyc = zs * fminf(fmaxf(py_*rz, -limy_e), limy_e);
            const float ja0 = FXc * rz;
            const float ja2 = -FXc * txc * rz * rz;
            const float jb1 = FYc * rz;
            const float jb2 = -FYc * tyc * rz * rz;

            const float c2d00 = ja0*ja0*C00 + 2.f*ja0*ja2*C02 + ja2*ja2*C22 + EPS2Dc;
            const float c2d01 = ja0*jb1*C01 + ja0*jb2*C02 + ja2*jb1*C12 + ja2*jb2*C22;
            const float c2d11 = jb1*jb1*C11 + 2.f*jb1*jb2*C12 + jb2*jb2*C22 + EPS2Dc;

            const float det2 = c2d00*c2d11 - c2d01*c2d01;
            valid = valid && (det2 > 1e-12f);
            const float rdet = 1.0f / (valid ? det2 : 1.0f);
            pA_ = c2d11 * rdet;             // conic a  (>0)
            pB_ = -c2d01 * rdet;            // conic b
            pC_ = c2d00 * rdet;             // conic c  (>0)

            pmx = FXc * px_ * rz + CXc;
            pmy = FYc * py_ * rz + CYc;

            pcr = fmaxf(C0c * sh0[3*p+0] + 0.5f, 0.0f);
            pcg = fmaxf(C0c * sh0[3*p+1] + 0.5f, 0.0f);
            pcb = fmaxf(C0c * sh0[3*p+2] + 0.5f, 0.0f);
            pop = 1.0f / (1.0f + __expf(-opacs[p]));
            pz  = pz_;

            // ---- EXACT cull: min over tile rect of sigma vs log(255*op) ----
            if (valid) {
                const float a_ = pA_, b_ = pB_, c_ = pC_;
                const float dx0 = tx0 - pmx, dx1 = tx1 - pmx;
                const float dy0 = ty0 - pmy, dy1 = ty1 - pmy;
                float smin;
                if (dx0 <= 0.f && 0.f <= dx1 && dy0 <= 0.f && 0.f <= dy1) {
                    smin = 0.f;
                } else {
                    const float ra = 1.0f / a_, rc = 1.0f / c_;
                    float yy = fminf(fmaxf(-b_ * dx0 * rc, dy0), dy1);
                    float s0 = 0.5f*a_*dx0*dx0 + b_*dx0*yy + 0.5f*c_*yy*yy;
                    yy = fminf(fmaxf(-b_ * dx1 * rc, dy0), dy1);
                    float s1 = 0.5f*a_*dx1*dx1 + b_*dx1*yy + 0.5f*c_*yy*yy;
                    float xx = fminf(fmaxf(-b_ * dy0 * ra, dx0), dx1);
                    float s2 = 0.5f*a_*xx*xx + b_*xx*dy0 + 0.5f*c_*dy0*dy0;
                    xx = fminf(fmaxf(-b_ * dy1 * ra, dx0), dx1);
                    float s3 = 0.5f*a_*xx*xx + b_*xx*dy1 + 0.5f*c_*dy1*dy1;
                    smin = fminf(fminf(s0, s1), fminf(s2, s3));
                }
                hit = (smin <= __logf(pop * 255.0f) + 1e-3f);
            }
        }
        phit = hit;
        mreg = __ballot(hit);
        if ((lt & 63) == 0) scnt[wave] = __popcll(mreg);
    }
    __syncthreads();

    if (lt == 0) {
        int acc = 0;
        for (int c = 0; c < nchunks; ++c) { sbase[c] = acc; acc += scnt[c]; }
        sbase[nchunks] = acc;
    }
    __syncthreads();
    const int k = sbase[nchunks];

    // compact survivor z's (original-index order == stable key order)
    int pslot = -1;
    if (lt < MAXP && phit) {
        pslot = sbase[wave] + __popcll(mreg & ((1ull << (lt & 63)) - 1ull));
        zc[pslot] = pz;
    }
    if (lt < 4) zc[k + lt] = INFINITY;
    __syncthreads();

    // stable rank-sort of survivors; scatter params from registers.
    // conic stored pre-halved on the diagonal: {mx,my,0.5a,b},{0.5c,op,crcg,cb}
    if (pslot >= 0) {
        const float za = pz;
        const int sa = pslot;
        int rank = 0;
        const float4* z4 = (const float4*)zc;
        const int k4 = (k + 3) >> 2;
        for (int j4 = 0; j4 < k4; ++j4) {
            const float4 v = z4[j4];
            const int j = j4 << 2;
            rank += (v.x < za || (v.x == za && (j+0) < sa));
            rank += (v.y < za || (v.y == za && (j+1) < sa));
            rank += (v.z < za || (v.z == za && (j+2) < sa));
            rank += (v.w < za || (v.w == za && (j+3) < sa));
        }
        unsigned ur = __float_as_uint(pcr);
        ur = (ur + 0x7FFFu + ((ur >> 16) & 1u)) & 0xFFFF0000u;
        unsigned ug = __float_as_uint(pcg);
        ug = (ug + 0x7FFFu + ((ug >> 16) & 1u)) >> 16;
        const float crcg = __uint_as_float(ur | ug);
        spts[rank][0] = make_float4(pmx, pmy, 0.5f * pA_, pB_);
        spts[rank][1] = make_float4(0.5f * pC_, pop, crcg, pcb);
    }
    __syncthreads();

    // ------- depth-parallel compositing: SEG segments x 128 thr x 2 px -------
    // packed-f32: the two pixels (rows r, r+8 of the same column) ride the
    // v_pk_* pipe; exp and the keep-select stay scalar per component.
    const int s  = lt >> 7;           // segment 0..7 (front..back)
    const int p0 = lt & 127;          // pixel 0 (rows 0..7), pixel 1 = p0+128
    const int col  = tx + (p0 & 15);
    const int row0 = ty + (p0 >> 4);
    const float px  = (float)col + 0.5f;
    const float py0 = (float)row0 + 0.5f;

    const int beg = (k * s) >> 3;             // SEG == 8
    const int end = (k * (s + 1)) >> 3;

    const v2f pyv = {py0, py0 + 8.0f};
    v2f T = {1.0f, 1.0f};
    v2f Rv = {0.f, 0.f}, Gv = {0.f, 0.f}, Bv = {0.f, 0.f};

    for (int base = beg; base < end; base += 4) {
        const int lim = (base + 4 < end) ? base + 4 : end;
        #pragma unroll 4
        for (int i = base; i < lim; ++i) {
            const float4 a4 = spts[i][0];        // mx, my, 0.5a, b
            const float4 b4 = spts[i][1];        // 0.5c, op, crcg(bf16x2), cb

            const float dx = px - a4.x;
            const v2f dy = pyv - a4.y;
            const float u = a4.z * dx * dx;          // 0.5a dx^2 (shared)
            const v2f tt = b4.x * dy + a4.w * dx;    // 0.5c dy + b dx   (pk)
            const v2f sg = dy * tt + u;              // sigma            (pk)

            const v2f e = {__expf(-sg.x), __expf(-sg.y)};
            v2f al = b4.y * e;                       // op * exp         (pk)
            al.x = fminf(al.x, 0.999f);
            al.y = fminf(al.y, 0.999f);
            al.x = ((sg.x >= 0.0f) && (al.x >= (1.0f/255.0f))) ? al.x : 0.0f;
            al.y = ((sg.y >= 0.0f) && (al.y >= (1.0f/255.0f))) ? al.y : 0.0f;

            const unsigned uc = __float_as_uint(b4.z);
            const float crf = __uint_as_float(uc & 0xFFFF0000u);
            const float cgf = __uint_as_float(uc << 16);

            const v2f w = T * al;                    // pk
            Rv += w * crf;                           // pk fma
            Gv += w * cgf;                           // pk fma
            Bv += w * b4.w;                          // pk fma
            T  -= al * T;                            // pk fma
        }
        if (!__any(fmaxf(T.x, T.y) > 1e-4f)) break;  // tail err <= ~1e-4
    }

    if (s > 0) {
        comb[s - 1][p0]       = make_float4(Rv.x, Gv.x, Bv.x, T.x);
        comb[s - 1][p0 + 128] = make_float4(Rv.y, Gv.y, Bv.y, T.y);
    }
    __syncthreads();

    if (s == 0) {
        // fold front-to-back for both pixels
        float rr = Rv.x, gg = Gv.x, bb = Bv.x, Tt = T.x;
        #pragma unroll
        for (int ss = 0; ss < SEG - 1; ++ss) {
            const float4 f = comb[ss][p0];
            rr += Tt * f.x; gg += Tt * f.y; bb += Tt * f.z; Tt *= f.w;
        }
        rr += Tt * BGc; gg += Tt * BGc; bb += Tt * BGc;
        int opix = row0 * W + col;
        out[3*opix + 0] = rr;
        out[3*opix + 1] = gg;
        out[3*opix + 2] = bb;
        out[3*npix + opix] = 1.0f - Tt;

        rr = Rv.y; gg = Gv.y; bb = Bv.y; Tt = T.y;
        #pragma unroll
        for (int ss = 0; ss < SEG - 1; ++ss) {
            const float4 f = comb[ss][p0 + 128];
            rr += Tt * f.x; gg += Tt * f.y; bb += Tt * f.z; Tt *= f.w;
        }
        rr += Tt * BGc; gg += Tt * BGc; bb += Tt * BGc;
        opix = (row0 + 8) * W + col;
        out[3*opix + 0] = rr;
        out[3*opix + 1] = gg;
        out[3*opix + 2] = bb;
        out[3*npix + opix] = 1.0f - Tt;
    }
}

extern "C" void kernel_launch(void* const* d_in, const int* in_sizes, int n_in,
                              void* d_out, int out_size, void* d_ws, size_t ws_size,
                              hipStream_t stream) {
    const float* cam    = (const float*)d_in[0];
    const float* means  = (const float*)d_in[1];
    const float* quats  = (const float*)d_in[2];
    const float* scales = (const float*)d_in[3];
    const float* opacs  = (const float*)d_in[4];
    const float* sh0    = (const float*)d_in[5];
    // d_in[6] = shN (unused by the reference render)
    const int* img_w = (const int*)d_in[8];

    const int n = in_sizes[4];            // N_PTS (== 512 for this problem)
    const int npix = out_size / 4;        // 3 color + 1 alpha per pixel

    const int blocks = npix / 256;        // one 16x16 tile per block
    gs_fused<<<blocks, 1024, 0, stream>>>(cam, means, quats, scales, opacs, sh0,
                                          img_w, (float*)d_out, n, npix);
}